// Round 6
// baseline (219.608 us; speedup 1.0000x reference)
//
#include <hip/hip_runtime.h>

// Correlation layer: out[b,o,h,w] = mean_c x1[b,c,h,w] * x2[b,c,h+dh,w+dw]
// B=8 C=128 H=W=128, d=4 -> 81 offsets (o = (dh+4)*9 + (dw+4)).
//
// R6 vs R5 (90 us, VALUBusy 38%, 9 waves/CU): registers bound occupancy
// (72 accs -> ~168 live regs -> 2.25 waves/SIMD), occupancy bound latency
// hiding. Halve thread state: 4 px/thread = 36 accs (~85 regs) and double
// the grid -> 18 waves/CU resident (4.5/SIMD).
//  - image row now = 32 lanes, so neighbor exchange uses wave_shr:1 /
//    wave_shl:1 DPP (whole-wave shift) + v_cndmask zeroing at image-row
//    boundary lanes (j==0 / j==31). Still ZERO LDS, zero barriers.
//  - keep: 2-deep register prefetch, batch-per-XCD swizzle.

constexpr int Bn = 8, Cn = 128, Hn = 128, Wn = 128;
constexpr int HWn = Hn * Wn;

__device__ __forceinline__ float wave_shr1(float x) {
  // lane i <- lane i-1 across the whole wave; lane 0 <- 0 (bound_ctrl)
  return __int_as_float(
      __builtin_amdgcn_update_dpp(0, __float_as_int(x), 0x138, 0xF, 0xF, true));
}
__device__ __forceinline__ float wave_shl1(float x) {
  // lane i <- lane i+1 across the whole wave; lane 63 <- 0 (bound_ctrl)
  return __int_as_float(
      __builtin_amdgcn_update_dpp(0, __float_as_int(x), 0x130, 0xF, 0xF, true));
}

__global__ __launch_bounds__(64, 5)
void corr_kernel(const float* __restrict__ x1, const float* __restrict__ x2,
                 float* __restrict__ out) {
  const int lane = threadIdx.x;       // 0..63
  const int half = lane >> 5;         // which row of the pair
  const int j    = lane & 31;         // px chunk within image row
  const int px0  = j << 2;            // 0,4,...,124

  // --- XCD swizzle: batch b on XCD b (round-robin assumption; perf-only) ---
  const int phys = blockIdx.x;        // 0..4607
  const int b    = phys & 7;
  const int s    = phys >> 3;         // 0..575
  const int dh   = s % 9 - 4;         // -4..4
  const int rowl = (s / 9) * 2 + half;
  const int x2row = rowl + dh;
  const bool ok = ((unsigned)x2row < (unsigned)Hn);  // per-lane, loop-invariant
  const bool jlo = (j == 0);
  const bool jhi = (j == 31);

  const float* x1p = x1 + (size_t)b * Cn * HWn + rowl * Wn + px0;
  const float* x2p = x2 + (size_t)b * Cn * HWn + x2row * Wn + px0;

  float4 acc[9];
#pragma unroll
  for (int dw = 0; dw < 9; ++dw) acc[dw] = make_float4(0.f, 0.f, 0.f, 0.f);

  const float4 fz = make_float4(0.f, 0.f, 0.f, 0.f);
  float4 A[2], B[2];
  // --- prologue: load channels 0 and 1 ---
#pragma unroll
  for (int p = 0; p < 2; ++p) {
    A[p] = *(const float4*)(x1p + (size_t)p * HWn);
    float4 t = fz;
    if (ok) t = *(const float4*)(x2p + (size_t)p * HWn);
    B[p] = t;
  }
  const float* pf1 = x1p + 2 * (size_t)HWn;
  const float* pf2 = x2p + 2 * (size_t)HWn;

#pragma unroll 2
  for (int cc = 0; cc < 128; ++cc) {
    const int sl = cc & 1;
    const float4 a  = A[sl];
    const float4 b0 = B[sl];
    // prefetch channel cc+2 into the freed slot (2-iter latency slack)
    if (cc < 126) {
      A[sl] = *(const float4*)pf1;
      float4 t = fz;
      if (ok) t = *(const float4*)pf2;
      B[sl] = t;
      pf1 += HWn;
      pf2 += HWn;
    }
    // window cols px0-4..px0+7 in registers: wave-shift DPP + boundary zeroing
    float p0 = wave_shr1(b0.x);   // col px0-4 (from lane i-1)
    float p1 = wave_shr1(b0.y);
    float p2 = wave_shr1(b0.z);
    float p3 = wave_shr1(b0.w);
    float n0 = wave_shl1(b0.x);   // col px0+4 (from lane i+1)
    float n1 = wave_shl1(b0.y);
    float n2 = wave_shl1(b0.z);
    float n3 = wave_shl1(b0.w);
    p0 = jlo ? 0.f : p0;  p1 = jlo ? 0.f : p1;
    p2 = jlo ? 0.f : p2;  p3 = jlo ? 0.f : p3;
    n0 = jhi ? 0.f : n0;  n1 = jhi ? 0.f : n1;
    n2 = jhi ? 0.f : n2;  n3 = jhi ? 0.f : n3;
    const float win[12] = {p0, p1, p2, p3, b0.x, b0.y, b0.z, b0.w,
                           n0, n1, n2, n3};
    // pixel jj (0..3) with offset dw-4 reads win[jj+dw]
#pragma unroll
    for (int dw = 0; dw < 9; ++dw) {
      acc[dw].x += a.x * win[dw + 0];
      acc[dw].y += a.y * win[dw + 1];
      acc[dw].z += a.z * win[dw + 2];
      acc[dw].w += a.w * win[dw + 3];
    }
  }

  // --- store: 9 dw planes x 4 px ---
  const float scale = 1.0f / 128.0f;
  const int obase = (dh + 4) * 9;
  float* ob = out + ((size_t)b * 81 + obase) * HWn + (size_t)rowl * Wn + px0;
#pragma unroll
  for (int dw = 0; dw < 9; ++dw) {
    float4 v = acc[dw];
    v.x *= scale; v.y *= scale; v.z *= scale; v.w *= scale;
    *(float4*)(ob + (size_t)dw * HWn) = v;
  }
}

extern "C" void kernel_launch(void* const* d_in, const int* in_sizes, int n_in,
                              void* d_out, int out_size, void* d_ws, size_t ws_size,
                              hipStream_t stream) {
  const float* x1 = (const float*)d_in[0];
  const float* x2 = (const float*)d_in[1];
  float* out = (float*)d_out;
  const int n_wgs = Bn * 9 * (Hn / 2);  // 4608 = 18 waves/CU
  corr_kernel<<<dim3(n_wgs), dim3(64), 0, stream>>>(x1, x2, out);
}